// Round 5
// baseline (288.138 us; speedup 1.0000x reference)
//
#include <hip/hip_runtime.h>
#include <hip/hip_fp16.h>
#include <stdint.h>

#define NN 4096      // nodes
#define FF 512       // in features
#define DD 64        // head dim
#define HH 4         // heads
#define MM 2         // metapaths
#define LOG2E 1.44269504088896340736f
#define ALPHA_LR 0.2f

typedef float f32x4 __attribute__((ext_vector_type(4)));
typedef _Float16 f16x8 __attribute__((ext_vector_type(8)));
typedef _Float16 f16x2 __attribute__((ext_vector_type(2)));
typedef unsigned short u16x2 __attribute__((ext_vector_type(2)));

extern "C" __device__ _Float16 __ocml_exp2_f16(_Float16);

union H4 { ushort4 u; _Float16 h[4]; };
union W8 { f16x8 v; uint32_t w[4]; f16x2 p[4]; };

__device__ inline float fast_exp2(float x) { return __builtin_amdgcn_exp2f(x); }
__device__ inline float fast_rcp(float x) { return __builtin_amdgcn_rcpf(x); }
__device__ inline f32x4 mfma16(f16x8 a, f16x8 b, f32x4 c) {
    return __builtin_amdgcn_mfma_f32_16x16x32_f16(a, b, c, 0, 0, 0);
}
// v_dot2_f32_f16: c += a[0]*b[0] + a[1]*b[1]
__device__ inline float fdot2_(f16x2 a, f16x2 b, float c) {
#if __has_builtin(__builtin_amdgcn_fdot2)
    return __builtin_amdgcn_fdot2(a, b, c, false);
#else
    return c + (float)a[0] * (float)b[0] + (float)a[1] * (float)b[1];
#endif
}
// order-preserving float->uint encode for atomicMax
__device__ inline uint32_t enc_f32(float f) {
    uint32_t u = __float_as_uint(f);
    return (u & 0x80000000u) ? ~u : (u | 0x80000000u);
}
__device__ inline float dec_f32(uint32_t k) {
    uint32_t u = (k & 0x80000000u) ? (k ^ 0x80000000u) : ~k;
    return __uint_as_float(u);
}
// packed f16 {0,1} mask for j-pair k from smeared bits V = rs8 | (rs8<<15)
__device__ inline f16x2 msk01(uint32_t V, int k) {
    uint32_t w = (V >> (2 * k)) & 0x00010001u;
    u16x2 m = __builtin_bit_cast(u16x2, w) * (u16x2){0x3C00, 0x3C00}; // v_pk_mul_lo_u16
    return __builtin_bit_cast(f16x2, m);
}
__device__ inline f16x2 pkmax(f16x2 a, f16x2 b) {
#if __has_builtin(__builtin_elementwise_max)
    return __builtin_elementwise_max(a, b);
#else
    return (f16x2){a[0] > b[0] ? a[0] : b[0], a[1] > b[1] ? a[1] : b[1]};
#endif
}

// ---- fused prep ----
// [0,2048): adj -> transposed bitmask. Sequential grid-stride reads (full
//           channel spread; measured-good) + ballot + lane-0 8B store.
//           Column-strip variant regressed (16KB-stride reads) — keep out.
// [2048,2560): W -> wtT f16 (+ m4a init)
__global__ __launch_bounds__(256) void k_prep(const int* __restrict__ adj,
                                              const float* __restrict__ W,
                                              _Float16* __restrict__ wt,
                                              unsigned long long* __restrict__ bitsT,
                                              uint32_t* __restrict__ m4a) {
    const int bid = blockIdx.x;
    if (bid < 2048) {
        const long long total = (long long)MM * NN * NN;      // 33554432
        const long long stride = 2048LL * 256;
        long long tid = (long long)bid * 256 + threadIdx.x;
        for (long long e = tid; e < total; e += stride) {
            unsigned long long msk = __ballot(adj[e] != 0);
            if ((threadIdx.x & 63) == 0) {
                long long q = e >> 6;
                int m  = (int)(q >> 18);
                int rem = (int)(q & 262143);
                int i  = rem >> 6;
                int jw = rem & 63;
                bitsT[((size_t)m * 64 + jw) * NN + i] = msk;
            }
        }
    } else {
        int t = (bid - 2048) * 256 + threadIdx.x;  // H*F*D = 131072
        if (t < HH) m4a[t] = 0u;                   // encoded floor
        int c = t >> 9, f = t & 511;
        int h = c >> 6, d = c & 63;
        wt[t] = (_Float16)W[(h * FF + f) * DD + d];
    }
}

// ---- Wh = x @ W[h] -> whT[h*64+d][n] f16 ; fused s1L/s2h/m4a from accumulators ----
__global__ __launch_bounds__(512) void k_wh(const float* __restrict__ x,
                                            const _Float16* __restrict__ wt,
                                            const float* __restrict__ a1,
                                            const float* __restrict__ a2,
                                            _Float16* __restrict__ whT,
                                            float* __restrict__ s1L,
                                            _Float16* __restrict__ s2h,
                                            uint32_t* __restrict__ m4a) {
    __shared__ float sred[8][2][16];
    const int wave = threadIdx.x >> 6;
    const int h    = wave & 3;
    const int th   = wave >> 2;
    const int lane = threadIdx.x & 63;
    const int iL   = lane & 15;
    const int quad = lane >> 4;
    const int i0   = blockIdx.x * 16;

    f32x4 acc[2];
    acc[0] = (f32x4){0.f, 0.f, 0.f, 0.f};
    acc[1] = (f32x4){0.f, 0.f, 0.f, 0.f};

    const float* arow = x + (size_t)(i0 + iL) * FF + quad * 8;
    const _Float16* bbase = wt + (size_t)(h * 64 + th * 32 + iL) * FF + quad * 8;

    for (int kc = 0; kc < FF; kc += 32) {
        f32x4 xa = *(const f32x4*)(arow + kc);
        f32x4 xb = *(const f32x4*)(arow + kc + 4);
        f16x8 a;
        #pragma unroll
        for (int r = 0; r < 4; ++r) {
            a[r]     = (_Float16)xa[r];
            a[4 + r] = (_Float16)xb[r];
        }
        #pragma unroll
        for (int u = 0; u < 2; ++u) {
            f16x8 b = *(const f16x8*)(bbase + (size_t)(16 * u) * FF + kc);
            acc[u] = mfma16(a, b, acc[u]);
        }
    }
    #pragma unroll
    for (int u = 0; u < 2; ++u) {
        H4 o;
        #pragma unroll
        for (int r = 0; r < 4; ++r) o.h[r] = (_Float16)acc[u][r];
        *(ushort4*)(whT + (size_t)(h * 64 + th * 32 + 16 * u + iL) * NN + i0 + quad * 4) = o.u;
    }

    const float a1v0 = a1[h * 64 + th * 32 + iL];
    const float a1v1 = a1[h * 64 + th * 32 + 16 + iL];
    const float a2v0 = a2[h * 64 + th * 32 + iL];
    const float a2v1 = a2[h * 64 + th * 32 + 16 + iL];
    #pragma unroll
    for (int r = 0; r < 4; ++r) {
        float p1 = acc[0][r] * a1v0 + acc[1][r] * a1v1;
        float p2 = acc[0][r] * a2v0 + acc[1][r] * a2v1;
        #pragma unroll
        for (int off = 1; off < 16; off <<= 1) {
            p1 += __shfl_xor(p1, off);
            p2 += __shfl_xor(p2, off);
        }
        if (iL == 0) {
            sred[wave][0][quad * 4 + r] = p1;
            sred[wave][1][quad * 4 + r] = p2;
        }
    }
    __syncthreads();
    if (threadIdx.x < 64) {
        int h2  = threadIdx.x >> 4;
        int idx = threadIdx.x & 15;
        float s1 = sred[h2][0][idx] + sred[h2 + 4][0][idx];
        float s2 = sred[h2][1][idx] + sred[h2 + 4][1][idx];
        float s2l = s2 * LOG2E;
        s1L[h2 * NN + i0 + idx] = s1 * LOG2E;
        s2h[h2 * NN + i0 + idx] = (_Float16)s2l;
        float mx = s2l;
        #pragma unroll
        for (int off = 1; off < 16; off <<= 1) mx = fmaxf(mx, __shfl_xor(mx, off));
        if (idx == 0) atomicMax(m4a + h2, enc_f32(mx));
    }
}

// ---- fused masked-attention + elu + metapath sum ----
// (512,1): 160 regs of live accumulator can never fit the 128-VGPR cap that
// any 4-wave/SIMD config imposes (round-1 spill storm) — so stay at
// 2 waves/SIMD and buy latency hiding with ILP instead:
//  * bfr/s2v (5 L2 loads per half, was load->use ~50cyc) double-buffered one
//    half ahead; bm (8 loads per it) double-buffered one it ahead.
//  * denominators via v_dot2_f32_f16 into d[4][2] (8 VGPR) instead of
//    accD[4][2] MFMA (32 VGPR) + bones (4) -> frees room for the buffers.
// All buffers named A/B, it-loop 2-unrolled: every index is compile-time.
__global__ __launch_bounds__(512, 1) void k_attn(const _Float16* __restrict__ whT,
                                                 const float* __restrict__ s1L,
                                                 const _Float16* __restrict__ s2h,
                                                 const uint32_t* __restrict__ m4a,
                                                 const unsigned long long* __restrict__ bitsT,
                                                 float* __restrict__ out) {
    __shared__ __align__(16) float xr[8][MM][4][16][16]; // [slot][m][t][col][row]
    __shared__ __align__(16) float dr[8][MM][16];

    const int tid  = threadIdx.x;
    const int wave = tid >> 6;
    const int lane = tid & 63;
    const int iL   = lane & 15;
    const int quad = lane >> 4;
    const int h    = blockIdx.x & 3;
    const int i0   = (blockIdx.x >> 2) * 64;      // 64 i-rows per block

    const float m4 = dec_f32(m4a[h]);
    f16x2 A2[4], B2[4];
    #pragma unroll
    for (int s = 0; s < 4; ++s) {
        float s1i = s1L[h * NN + i0 + 16 * s + iL];
        float vv  = s1i + m4;
        float cii = fmaxf(vv, ALPHA_LR * vv);     // lrelu row shift (log2 domain)
        _Float16 a = (_Float16)(s1i - cii);
        _Float16 b = (_Float16)(ALPHA_LR * s1i - cii);
        A2[s] = (f16x2){a, a};
        B2[s] = (f16x2){b, b};
    }
    const f16x2 al2 = (f16x2){(_Float16)ALPHA_LR, (_Float16)ALPHA_LR};
    const f16x2 one2 = (f16x2){(_Float16)1.0f, (_Float16)1.0f};

    f32x4 acc[4][MM][4];
    float dden[4][MM];
    #pragma unroll
    for (int s = 0; s < 4; ++s)
        #pragma unroll
        for (int m = 0; m < MM; ++m) {
            dden[s][m] = 0.f;
            #pragma unroll
            for (int t = 0; t < 4; ++t) acc[s][m][t] = (f32x4){0.f, 0.f, 0.f, 0.f};
        }

    const _Float16* s2row = s2h + h * NN;
    const _Float16* brow = whT + (size_t)(h * 64 + iL) * NN;   // + 16t*NN + j
    const int qshift = quad * 8;
    const int jbase = wave * 512;

// operand loads for step (ITV, HALF); address masked so the one-step-over
// prefetch at the tail stays in-bounds (value unused)
#define LOADS(BFR, S2V, ITV, HALF)                                              \
    do {                                                                        \
        const int jb_ = ((jbase + (ITV) * 64 + 32 * (HALF)) & (NN - 1)) + qshift; \
        _Pragma("unroll")                                                       \
        for (int t = 0; t < 4; ++t)                                             \
            BFR[t] = *(const f16x8*)(brow + (size_t)(16 * t) * NN + jb_);       \
        S2V.v = *(const f16x8*)(s2row + jb_);                                   \
    } while (0)

#define BMLOAD(BM, ITV)                                                         \
    do {                                                                        \
        const int jw_ = ((jbase + (ITV) * 64) >> 6) & 63;                       \
        const unsigned long long* bp_ = bitsT + (size_t)jw_ * NN + i0 + iL;     \
        _Pragma("unroll")                                                       \
        for (int m = 0; m < MM; ++m)                                            \
            _Pragma("unroll")                                                   \
            for (int s = 0; s < 4; ++s)                                         \
                BM[m][s] = bp_[(size_t)m * 64 * NN + 16 * s];                   \
    } while (0)

#define COMPUTE(HALF, BM, BFR, S2V)                                             \
    do {                                                                        \
        const int shft_ = 32 * (HALF) + qshift;                                 \
        _Pragma("unroll")                                                       \
        for (int s = 0; s < 4; ++s) {                                           \
            uint32_t rs0 = (uint32_t)(BM[0][s] >> shft_) & 0xFFu;               \
            uint32_t rs1 = (uint32_t)(BM[1][s] >> shft_) & 0xFFu;               \
            uint32_t V0 = rs0 | (rs0 << 15);                                    \
            uint32_t V1 = rs1 | (rs1 << 15);                                    \
            W8 a0, a1v;                                                         \
            _Pragma("unroll")                                                   \
            for (int k = 0; k < 4; ++k) {                                       \
                f16x2 z = S2V.p[k] + A2[s];               /* v_pk_add_f16 */    \
                f16x2 l = al2 * S2V.p[k] + B2[s];         /* v_pk_fma_f16 */    \
                f16x2 mx = pkmax(z, l);                   /* v_pk_max_f16 */    \
                f16x2 p = (f16x2){__ocml_exp2_f16(mx[0]), __ocml_exp2_f16(mx[1])}; \
                a0.p[k]  = p * msk01(V0, k);                                    \
                a1v.p[k] = p * msk01(V1, k);                                    \
            }                                                                   \
            _Pragma("unroll")                                                   \
            for (int t = 0; t < 4; ++t) {                                       \
                acc[s][0][t] = mfma16(a0.v, BFR[t], acc[s][0][t]);              \
                acc[s][1][t] = mfma16(a1v.v, BFR[t], acc[s][1][t]);             \
            }                                                                   \
            _Pragma("unroll")                                                   \
            for (int k = 0; k < 4; ++k) {                                       \
                dden[s][0] = fdot2_(a0.p[k], one2, dden[s][0]);                 \
                dden[s][1] = fdot2_(a1v.p[k], one2, dden[s][1]);                \
            }                                                                   \
        }                                                                       \
    } while (0)

    unsigned long long bmA[MM][4], bmB[MM][4];
    f16x8 bfrA[4], bfrB[4];
    W8 s2vA, s2vB;

    BMLOAD(bmA, 0);
    LOADS(bfrA, s2vA, 0, 0);
    #pragma unroll 1
    for (int it = 0; it < 8; it += 2) {
        // ---- even it: masks in bmA ----
        LOADS(bfrB, s2vB, it, 1);          // prefetch half 1
        BMLOAD(bmB, it + 1);               // prefetch next it's masks
        COMPUTE(0, bmA, bfrA, s2vA);
        LOADS(bfrA, s2vA, it + 1, 0);      // prefetch next it's half 0
        COMPUTE(1, bmA, bfrB, s2vB);
        // ---- odd it: masks in bmB ----
        LOADS(bfrB, s2vB, it + 1, 1);
        BMLOAD(bmA, it + 2);               // it=6 -> loads (masked) it=8, unused
        COMPUTE(0, bmB, bfrA, s2vA);
        LOADS(bfrA, s2vA, it + 2, 0);      // it=6 -> masked prefetch, unused
        COMPUTE(1, bmB, bfrB, s2vB);
    }
#undef LOADS
#undef BMLOAD
#undef COMPUTE

    // ---- epilogue: per s, single 8-slot store + 4-wave finalize ----
    // unrolled: acc[s]/dden[s] statically indexed (runtime-indexed ext_vector
    // arrays go to scratch)
    #pragma unroll
    for (int s = 0; s < 4; ++s) {
        __syncthreads();          // previous round's reads complete
        #pragma unroll
        for (int m = 0; m < MM; ++m) {
            #pragma unroll
            for (int t = 0; t < 4; ++t)
                *(f32x4*)&xr[wave][m][t][iL][quad * 4] = acc[s][m][t];
        }
        {   // denominator: quad-reduce (k-partials live in the 4 quads of row iL)
            float d0v = dden[s][0];
            float d1v = dden[s][1];
            d0v += __shfl_xor(d0v, 16); d0v += __shfl_xor(d0v, 32);
            d1v += __shfl_xor(d1v, 16); d1v += __shfl_xor(d1v, 32);
            if (quad == 0) {
                dr[wave][0][iL] = d0v;
                dr[wave][1][iL] = d1v;
            }
        }
        __syncthreads();
        if (wave < 4) {
            const int t = wave;
            f32x4 n0 = (f32x4){0.f, 0.f, 0.f, 0.f};
            f32x4 n1 = (f32x4){0.f, 0.f, 0.f, 0.f};
            f32x4 d0 = (f32x4){0.f, 0.f, 0.f, 0.f};
            f32x4 d1 = (f32x4){0.f, 0.f, 0.f, 0.f};
            #pragma unroll
            for (int sl = 0; sl < 8; ++sl) {
                n0 += *(const f32x4*)&xr[sl][0][t][iL][quad * 4];
                n1 += *(const f32x4*)&xr[sl][1][t][iL][quad * 4];
                d0 += *(const f32x4*)&dr[sl][0][quad * 4];
                d1 += *(const f32x4*)&dr[sl][1][quad * 4];
            }
            const int i0s = i0 + 16 * s;
            #pragma unroll
            for (int r = 0; r < 4; ++r) {
                float v0 = n0[r] * fast_rcp(d0[r]);
                float v1 = n1[r] * fast_rcp(d1[r]);
                float e0 = v0 > 0.f ? v0 : (fast_exp2(v0 * LOG2E) - 1.f);
                float e1 = v1 > 0.f ? v1 : (fast_exp2(v1 * LOG2E) - 1.f);
                out[(size_t)(i0s + quad * 4 + r) * (HH * DD) + h * 64 + 16 * t + iL] = e0 + e1;
            }
        }
    }
}

extern "C" void kernel_launch(void* const* d_in, const int* in_sizes, int n_in,
                              void* d_out, int out_size, void* d_ws, size_t ws_size,
                              hipStream_t stream) {
    const float* x   = (const float*)d_in[0];
    const int*   adj = (const int*)d_in[1];
    const float* W   = (const float*)d_in[2];
    const float* a1  = (const float*)d_in[3];
    const float* a2  = (const float*)d_in[4];
    // d_in[5..7] (Ws, bs, q_sem) mathematically dead: softmax over size-1 axis == 1
    float* out = (float*)d_out;

    char* ws = (char*)d_ws;
    _Float16* wt   = (_Float16*)(ws);                 // 256 KB
    _Float16* whT  = (_Float16*)(ws + 262144);        // 2 MB
    float*    s1L  = (float*)(ws + 2359296);          // 64 KB
    _Float16* s2h  = (_Float16*)(ws + 2424832);       // 32 KB
    uint32_t* m4a  = (uint32_t*)(ws + 2457600);       // 16 B
    unsigned long long* bitsT = (unsigned long long*)(ws + 2490368); // 4 MB

    hipLaunchKernelGGL(k_prep, dim3(2560), dim3(256), 0, stream,
                       adj, W, wt, bitsT, m4a);
    hipLaunchKernelGGL(k_wh, dim3(256), dim3(512), 0, stream,
                       x, wt, a1, a2, whT, s1L, s2h, m4a);
    hipLaunchKernelGGL(k_attn, dim3(256), dim3(512), 0, stream,
                       whT, s1L, s2h, m4a, bitsT, out);
}

// Round 6
// 287.253 us; speedup vs baseline: 1.0031x; 1.0031x over previous
//
#include <hip/hip_runtime.h>
#include <hip/hip_fp16.h>
#include <stdint.h>

#define NN 4096      // nodes
#define FF 512       // in features
#define DD 64        // head dim
#define HH 4         // heads
#define MM 2         // metapaths
#define LOG2E 1.44269504088896340736f
#define ALPHA_LR 0.2f

typedef float f32x4 __attribute__((ext_vector_type(4)));
typedef _Float16 f16x8 __attribute__((ext_vector_type(8)));
typedef _Float16 f16x2 __attribute__((ext_vector_type(2)));
typedef unsigned short u16x2 __attribute__((ext_vector_type(2)));

extern "C" __device__ _Float16 __ocml_exp2_f16(_Float16);

union H4 { ushort4 u; _Float16 h[4]; };
union W8 { f16x8 v; uint32_t w[4]; f16x2 p[4]; };

__device__ inline float fast_exp2(float x) { return __builtin_amdgcn_exp2f(x); }
__device__ inline float fast_rcp(float x) { return __builtin_amdgcn_rcpf(x); }
__device__ inline f32x4 mfma16(f16x8 a, f16x8 b, f32x4 c) {
    return __builtin_amdgcn_mfma_f32_16x16x32_f16(a, b, c, 0, 0, 0);
}
// order-preserving float->uint encode for atomicMax
__device__ inline uint32_t enc_f32(float f) {
    uint32_t u = __float_as_uint(f);
    return (u & 0x80000000u) ? ~u : (u | 0x80000000u);
}
__device__ inline float dec_f32(uint32_t k) {
    uint32_t u = (k & 0x80000000u) ? (k ^ 0x80000000u) : ~k;
    return __uint_as_float(u);
}
// packed f16 {0,1} mask for j-pair k from smeared bits V = rs8 | (rs8<<15)
__device__ inline f16x2 msk01(uint32_t V, int k) {
    uint32_t w = (V >> (2 * k)) & 0x00010001u;
    u16x2 m = __builtin_bit_cast(u16x2, w) * (u16x2){0x3C00, 0x3C00}; // v_pk_mul_lo_u16
    return __builtin_bit_cast(f16x2, m);
}
__device__ inline f16x2 pkmax(f16x2 a, f16x2 b) {
#if __has_builtin(__builtin_elementwise_max)
    return __builtin_elementwise_max(a, b);
#else
    return (f16x2){a[0] > b[0] ? a[0] : b[0], a[1] > b[1] ? a[1] : b[1]};
#endif
}

// ---- fused prep ----
// [0,2048): adj -> transposed bitmask. Sequential grid-stride reads (full
//           channel spread; measured-good) + ballot + lane-0 8B store.
//           Column-strip variant regressed (16KB-stride reads) — keep out.
// [2048,2560): W -> wtT f16 (+ m4a init)
__global__ __launch_bounds__(256) void k_prep(const int* __restrict__ adj,
                                              const float* __restrict__ W,
                                              _Float16* __restrict__ wt,
                                              unsigned long long* __restrict__ bitsT,
                                              uint32_t* __restrict__ m4a) {
    const int bid = blockIdx.x;
    if (bid < 2048) {
        const long long total = (long long)MM * NN * NN;      // 33554432
        const long long stride = 2048LL * 256;
        long long tid = (long long)bid * 256 + threadIdx.x;
        for (long long e = tid; e < total; e += stride) {
            unsigned long long msk = __ballot(adj[e] != 0);
            if ((threadIdx.x & 63) == 0) {
                long long q = e >> 6;
                int m  = (int)(q >> 18);
                int rem = (int)(q & 262143);
                int i  = rem >> 6;
                int jw = rem & 63;
                bitsT[((size_t)m * 64 + jw) * NN + i] = msk;
            }
        }
    } else {
        int t = (bid - 2048) * 256 + threadIdx.x;  // H*F*D = 131072
        if (t < HH) m4a[t] = 0u;                   // encoded floor
        int c = t >> 9, f = t & 511;
        int h = c >> 6, d = c & 63;
        wt[t] = (_Float16)W[(h * FF + f) * DD + d];
    }
}

// ---- Wh = x @ W[h] -> whT[h*64+d][n] f16 ; fused s1L/s2h/m4a from accumulators ----
__global__ __launch_bounds__(512) void k_wh(const float* __restrict__ x,
                                            const _Float16* __restrict__ wt,
                                            const float* __restrict__ a1,
                                            const float* __restrict__ a2,
                                            _Float16* __restrict__ whT,
                                            float* __restrict__ s1L,
                                            _Float16* __restrict__ s2h,
                                            uint32_t* __restrict__ m4a) {
    __shared__ float sred[8][2][16];
    const int wave = threadIdx.x >> 6;
    const int h    = wave & 3;
    const int th   = wave >> 2;
    const int lane = threadIdx.x & 63;
    const int iL   = lane & 15;
    const int quad = lane >> 4;
    const int i0   = blockIdx.x * 16;

    f32x4 acc[2];
    acc[0] = (f32x4){0.f, 0.f, 0.f, 0.f};
    acc[1] = (f32x4){0.f, 0.f, 0.f, 0.f};

    const float* arow = x + (size_t)(i0 + iL) * FF + quad * 8;
    const _Float16* bbase = wt + (size_t)(h * 64 + th * 32 + iL) * FF + quad * 8;

    for (int kc = 0; kc < FF; kc += 32) {
        f32x4 xa = *(const f32x4*)(arow + kc);
        f32x4 xb = *(const f32x4*)(arow + kc + 4);
        f16x8 a;
        #pragma unroll
        for (int r = 0; r < 4; ++r) {
            a[r]     = (_Float16)xa[r];
            a[4 + r] = (_Float16)xb[r];
        }
        #pragma unroll
        for (int u = 0; u < 2; ++u) {
            f16x8 b = *(const f16x8*)(bbase + (size_t)(16 * u) * FF + kc);
            acc[u] = mfma16(a, b, acc[u]);
        }
    }
    #pragma unroll
    for (int u = 0; u < 2; ++u) {
        H4 o;
        #pragma unroll
        for (int r = 0; r < 4; ++r) o.h[r] = (_Float16)acc[u][r];
        *(ushort4*)(whT + (size_t)(h * 64 + th * 32 + 16 * u + iL) * NN + i0 + quad * 4) = o.u;
    }

    const float a1v0 = a1[h * 64 + th * 32 + iL];
    const float a1v1 = a1[h * 64 + th * 32 + 16 + iL];
    const float a2v0 = a2[h * 64 + th * 32 + iL];
    const float a2v1 = a2[h * 64 + th * 32 + 16 + iL];
    #pragma unroll
    for (int r = 0; r < 4; ++r) {
        float p1 = acc[0][r] * a1v0 + acc[1][r] * a1v1;
        float p2 = acc[0][r] * a2v0 + acc[1][r] * a2v1;
        #pragma unroll
        for (int off = 1; off < 16; off <<= 1) {
            p1 += __shfl_xor(p1, off);
            p2 += __shfl_xor(p2, off);
        }
        if (iL == 0) {
            sred[wave][0][quad * 4 + r] = p1;
            sred[wave][1][quad * 4 + r] = p2;
        }
    }
    __syncthreads();
    if (threadIdx.x < 64) {
        int h2  = threadIdx.x >> 4;
        int idx = threadIdx.x & 15;
        float s1 = sred[h2][0][idx] + sred[h2 + 4][0][idx];
        float s2 = sred[h2][1][idx] + sred[h2 + 4][1][idx];
        float s2l = s2 * LOG2E;
        s1L[h2 * NN + i0 + idx] = s1 * LOG2E;
        s2h[h2 * NN + i0 + idx] = (_Float16)s2l;
        float mx = s2l;
        #pragma unroll
        for (int off = 1; off < 16; off <<= 1) mx = fmaxf(mx, __shfl_xor(mx, off));
        if (idx == 0) atomicMax(m4a + h2, enc_f32(mx));
    }
}

// ---- fused masked-attention + elu + metapath sum ----
// OCCUPANCY RESTRUCTURE: 32 i-rows per block (s in {0,1}), grid 512 =
// (128 i-groups) x (4 heads) = 2 blocks/CU. Accumulator state drops to
// acc[2][2][4]+accD[2][2] = 80 VGPR, total working set ~120-126, which
// FITS the 128-VGPR cap that (512,2) imposes -> 4 waves/SIMD, 2x the TLP
// of the old 1-block/CU config, no spill (round-1: spill is catastrophic;
// round-5: manual SW-pipeline at 2 waves/SIMD regressed — TLP, not ILP,
// is the right tool for this latency-bound loop). LDS 65KB x 2 = 130 <= 160.
// Simple non-pipelined loop (compiler schedules loads fine); MFMA-pipe
// denominator (accD x bones) — keeps the heavy VALU pipe free.
__global__ __launch_bounds__(512, 2) void k_attn(const _Float16* __restrict__ whT,
                                                 const float* __restrict__ s1L,
                                                 const _Float16* __restrict__ s2h,
                                                 const uint32_t* __restrict__ m4a,
                                                 const unsigned long long* __restrict__ bitsT,
                                                 float* __restrict__ out) {
    __shared__ __align__(16) float xr[8][MM][4][16][16]; // [slot][m][t][col][row] 64KB
    __shared__ __align__(16) float dr[8][MM][16];        // 1KB

    const int tid  = threadIdx.x;
    const int wave = tid >> 6;
    const int lane = tid & 63;
    const int iL   = lane & 15;
    const int quad = lane >> 4;
    const int h    = blockIdx.x & 3;
    const int i0   = (blockIdx.x >> 2) * 32;      // 32 i-rows per block

    const float m4 = dec_f32(m4a[h]);
    f16x2 A2[2], B2[2];
    #pragma unroll
    for (int s = 0; s < 2; ++s) {
        float s1i = s1L[h * NN + i0 + 16 * s + iL];
        float vv  = s1i + m4;
        float cii = fmaxf(vv, ALPHA_LR * vv);     // lrelu row shift (log2 domain)
        _Float16 a = (_Float16)(s1i - cii);
        _Float16 b = (_Float16)(ALPHA_LR * s1i - cii);
        A2[s] = (f16x2){a, a};
        B2[s] = (f16x2){b, b};
    }
    const f16x2 al2 = (f16x2){(_Float16)ALPHA_LR, (_Float16)ALPHA_LR};

    f32x4 acc[2][MM][4];
    f32x4 accD[2][MM];
    #pragma unroll
    for (int s = 0; s < 2; ++s)
        #pragma unroll
        for (int m = 0; m < MM; ++m) {
            accD[s][m] = (f32x4){0.f, 0.f, 0.f, 0.f};
            #pragma unroll
            for (int t = 0; t < 4; ++t) acc[s][m][t] = (f32x4){0.f, 0.f, 0.f, 0.f};
        }

    f16x8 bones;
    #pragma unroll
    for (int e = 0; e < 8; ++e) bones[e] = (_Float16)1.0f;

    const _Float16* s2row = s2h + h * NN;
    const _Float16* brow = whT + (size_t)(h * 64 + iL) * NN;   // + 16t*NN + j
    const int qshift = quad * 8;
    const int jbase = wave * 512;

    const unsigned long long* pB[MM][2];
    #pragma unroll
    for (int m = 0; m < MM; ++m)
        #pragma unroll
        for (int s = 0; s < 2; ++s)
            pB[m][s] = bitsT + (size_t)m * 64 * NN + i0 + 16 * s + iL;

    #pragma unroll 1
    for (int it = 0; it < 8; ++it) {
        const int jc = jbase + it * 64;
        const int jw = jc >> 6;
        unsigned long long bm[MM][2];
        #pragma unroll
        for (int m = 0; m < MM; ++m)
            #pragma unroll
            for (int s = 0; s < 2; ++s)
                bm[m][s] = pB[m][s][(size_t)jw * NN];

        #pragma unroll
        for (int half = 0; half < 2; ++half) {
            const int jb = jc + 32 * half;
            const W8 s2v = *(const W8*)(s2row + jb + qshift);  // 8 f16 (4 pairs)
            const int shft = 32 * half + qshift;

            // P[s][m]: masked exp weights for this (half, quad) — 16 VGPR
            W8 P[2][MM];
            #pragma unroll
            for (int s = 0; s < 2; ++s) {
                uint32_t rs0 = (uint32_t)(bm[0][s] >> shft) & 0xFFu;
                uint32_t rs1 = (uint32_t)(bm[1][s] >> shft) & 0xFFu;
                uint32_t V0 = rs0 | (rs0 << 15);   // bit 2k+1 -> bit 2k+16
                uint32_t V1 = rs1 | (rs1 << 15);
                #pragma unroll
                for (int k = 0; k < 4; ++k) {
                    f16x2 z = s2v.p[k] + A2[s];               // v_pk_add_f16
                    f16x2 l = al2 * s2v.p[k] + B2[s];         // v_pk_fma_f16
                    f16x2 mx = pkmax(z, l);                   // v_pk_max_f16
                    f16x2 p = (f16x2){__ocml_exp2_f16(mx[0]), __ocml_exp2_f16(mx[1])};
                    P[s][0].p[k] = p * msk01(V0, k);          // v_pk_mul_f16
                    P[s][1].p[k] = p * msk01(V1, k);
                }
                accD[s][0] = mfma16(P[s][0].v, bones, accD[s][0]);
                accD[s][1] = mfma16(P[s][1].v, bones, accD[s][1]);
            }
            // whT fragments loaded ONCE per half, shared across both s
            #pragma unroll
            for (int t = 0; t < 4; ++t) {
                f16x8 bfr = *(const f16x8*)(brow + (size_t)(16 * t) * NN + jb + qshift);
                #pragma unroll
                for (int s = 0; s < 2; ++s) {
                    acc[s][0][t] = mfma16(P[s][0].v, bfr, acc[s][0][t]);
                    acc[s][1][t] = mfma16(P[s][1].v, bfr, acc[s][1][t]);
                }
            }
        }
    }

    // ---- epilogue: per s, single 8-slot store + 4-wave finalize ----
    // unrolled: acc[s] statically indexed (runtime-indexed ext_vector arrays
    // go to scratch)
    #pragma unroll
    for (int s = 0; s < 2; ++s) {
        __syncthreads();          // previous round's reads complete
        #pragma unroll
        for (int m = 0; m < MM; ++m) {
            #pragma unroll
            for (int t = 0; t < 4; ++t)
                *(f32x4*)&xr[wave][m][t][iL][quad * 4] = acc[s][m][t];
            if (iL == 0) *(f32x4*)&dr[wave][m][quad * 4] = accD[s][m];
        }
        __syncthreads();
        if (wave < 4) {
            const int t = wave;
            f32x4 n0 = (f32x4){0.f, 0.f, 0.f, 0.f};
            f32x4 n1 = (f32x4){0.f, 0.f, 0.f, 0.f};
            f32x4 d0 = (f32x4){0.f, 0.f, 0.f, 0.f};
            f32x4 d1 = (f32x4){0.f, 0.f, 0.f, 0.f};
            #pragma unroll
            for (int sl = 0; sl < 8; ++sl) {
                n0 += *(const f32x4*)&xr[sl][0][t][iL][quad * 4];
                n1 += *(const f32x4*)&xr[sl][1][t][iL][quad * 4];
                d0 += *(const f32x4*)&dr[sl][0][quad * 4];
                d1 += *(const f32x4*)&dr[sl][1][quad * 4];
            }
            const int i0s = i0 + 16 * s;
            #pragma unroll
            for (int r = 0; r < 4; ++r) {
                float v0 = n0[r] * fast_rcp(d0[r]);
                float v1 = n1[r] * fast_rcp(d1[r]);
                float e0 = v0 > 0.f ? v0 : (fast_exp2(v0 * LOG2E) - 1.f);
                float e1 = v1 > 0.f ? v1 : (fast_exp2(v1 * LOG2E) - 1.f);
                out[(size_t)(i0s + quad * 4 + r) * (HH * DD) + h * 64 + 16 * t + iL] = e0 + e1;
            }
        }
    }
}

extern "C" void kernel_launch(void* const* d_in, const int* in_sizes, int n_in,
                              void* d_out, int out_size, void* d_ws, size_t ws_size,
                              hipStream_t stream) {
    const float* x   = (const float*)d_in[0];
    const int*   adj = (const int*)d_in[1];
    const float* W   = (const float*)d_in[2];
    const float* a1  = (const float*)d_in[3];
    const float* a2  = (const float*)d_in[4];
    // d_in[5..7] (Ws, bs, q_sem) mathematically dead: softmax over size-1 axis == 1
    float* out = (float*)d_out;

    char* ws = (char*)d_ws;
    _Float16* wt   = (_Float16*)(ws);                 // 256 KB
    _Float16* whT  = (_Float16*)(ws + 262144);        // 2 MB
    float*    s1L  = (float*)(ws + 2359296);          // 64 KB
    _Float16* s2h  = (_Float16*)(ws + 2424832);       // 32 KB
    uint32_t* m4a  = (uint32_t*)(ws + 2457600);       // 16 B
    unsigned long long* bitsT = (unsigned long long*)(ws + 2490368); // 4 MB

    hipLaunchKernelGGL(k_prep, dim3(2560), dim3(256), 0, stream,
                       adj, W, wt, bitsT, m4a);
    hipLaunchKernelGGL(k_wh, dim3(256), dim3(512), 0, stream,
                       x, wt, a1, a2, whT, s1L, s2h, m4a);
    hipLaunchKernelGGL(k_attn, dim3(512), dim3(512), 0, stream,
                       whT, s1L, s2h, m4a, bitsT, out);
}

// Round 7
// 270.913 us; speedup vs baseline: 1.0636x; 1.0603x over previous
//
#include <hip/hip_runtime.h>
#include <hip/hip_fp16.h>
#include <stdint.h>

#define NN 4096      // nodes
#define FF 512       // in features
#define DD 64        // head dim
#define HH 4         // heads
#define MM 2         // metapaths
#define LOG2E 1.44269504088896340736f
#define ALPHA_LR 0.2f

typedef float f32x4 __attribute__((ext_vector_type(4)));
typedef _Float16 f16x8 __attribute__((ext_vector_type(8)));
typedef _Float16 f16x2 __attribute__((ext_vector_type(2)));
typedef unsigned short u16x2 __attribute__((ext_vector_type(2)));

extern "C" __device__ _Float16 __ocml_exp2_f16(_Float16);

union H4 { ushort4 u; _Float16 h[4]; };
union W8 { f16x8 v; uint32_t w[4]; f16x2 p[4]; };

__device__ inline float fast_exp2(float x) { return __builtin_amdgcn_exp2f(x); }
__device__ inline float fast_rcp(float x) { return __builtin_amdgcn_rcpf(x); }
__device__ inline f32x4 mfma16(f16x8 a, f16x8 b, f32x4 c) {
    return __builtin_amdgcn_mfma_f32_16x16x32_f16(a, b, c, 0, 0, 0);
}
// order-preserving float->uint encode for atomicMax
__device__ inline uint32_t enc_f32(float f) {
    uint32_t u = __float_as_uint(f);
    return (u & 0x80000000u) ? ~u : (u | 0x80000000u);
}
__device__ inline float dec_f32(uint32_t k) {
    uint32_t u = (k & 0x80000000u) ? (k ^ 0x80000000u) : ~k;
    return __uint_as_float(u);
}
// packed f16 {0,1} mask for j-pair k from smeared bits V = rs8 | (rs8<<15)
__device__ inline f16x2 msk01(uint32_t V, int k) {
    uint32_t w = (V >> (2 * k)) & 0x00010001u;
    u16x2 m = __builtin_bit_cast(u16x2, w) * (u16x2){0x3C00, 0x3C00}; // v_pk_mul_lo_u16
    return __builtin_bit_cast(f16x2, m);
}
__device__ inline f16x2 pkmax(f16x2 a, f16x2 b) {
#if __has_builtin(__builtin_elementwise_max)
    return __builtin_elementwise_max(a, b);
#else
    return (f16x2){a[0] > b[0] ? a[0] : b[0], a[1] > b[1] ? a[1] : b[1]};
#endif
}

// global -> LDS direct (16B/lane x 64 lanes = 1KB per call); LDS dest is
// wave-uniform base + lane*16 (linear), so swizzling is done on the SOURCE
// lane->address mapping (rule: both-sides-or-neither).
#define GLOAD_LDS(G, L)                                                     \
    __builtin_amdgcn_global_load_lds(                                       \
        (const __attribute__((address_space(1))) void*)(G),                 \
        (__attribute__((address_space(3))) void*)(L), 16, 0, 0)

// ---- fused prep ----
// [0,2048): adj -> transposed bitmask. Sequential grid-stride reads (full
//           channel spread; measured-good) + ballot + lane-0 8B store.
//           Column-strip variant regressed (16KB-stride reads) — keep out.
// [2048,2560): W -> wtT f16 (+ m4a init)
__global__ __launch_bounds__(256) void k_prep(const int* __restrict__ adj,
                                              const float* __restrict__ W,
                                              _Float16* __restrict__ wt,
                                              unsigned long long* __restrict__ bitsT,
                                              uint32_t* __restrict__ m4a) {
    const int bid = blockIdx.x;
    if (bid < 2048) {
        const long long total = (long long)MM * NN * NN;      // 33554432
        const long long stride = 2048LL * 256;
        long long tid = (long long)bid * 256 + threadIdx.x;
        for (long long e = tid; e < total; e += stride) {
            unsigned long long msk = __ballot(adj[e] != 0);
            if ((threadIdx.x & 63) == 0) {
                long long q = e >> 6;
                int m  = (int)(q >> 18);
                int rem = (int)(q & 262143);
                int i  = rem >> 6;
                int jw = rem & 63;
                bitsT[((size_t)m * 64 + jw) * NN + i] = msk;
            }
        }
    } else {
        int t = (bid - 2048) * 256 + threadIdx.x;  // H*F*D = 131072
        if (t < HH) m4a[t] = 0u;                   // encoded floor
        int c = t >> 9, f = t & 511;
        int h = c >> 6, d = c & 63;
        wt[t] = (_Float16)W[(h * FF + f) * DD + d];
    }
}

// ---- Wh = x @ W[h] -> whT[h*64+d][n] f16 ; fused s1L/s2h/m4a from accumulators ----
__global__ __launch_bounds__(512) void k_wh(const float* __restrict__ x,
                                            const _Float16* __restrict__ wt,
                                            const float* __restrict__ a1,
                                            const float* __restrict__ a2,
                                            _Float16* __restrict__ whT,
                                            float* __restrict__ s1L,
                                            _Float16* __restrict__ s2h,
                                            uint32_t* __restrict__ m4a) {
    __shared__ float sred[8][2][16];
    const int wave = threadIdx.x >> 6;
    const int h    = wave & 3;
    const int th   = wave >> 2;
    const int lane = threadIdx.x & 63;
    const int iL   = lane & 15;
    const int quad = lane >> 4;
    const int i0   = blockIdx.x * 16;

    f32x4 acc[2];
    acc[0] = (f32x4){0.f, 0.f, 0.f, 0.f};
    acc[1] = (f32x4){0.f, 0.f, 0.f, 0.f};

    const float* arow = x + (size_t)(i0 + iL) * FF + quad * 8;
    const _Float16* bbase = wt + (size_t)(h * 64 + th * 32 + iL) * FF + quad * 8;

    for (int kc = 0; kc < FF; kc += 32) {
        f32x4 xa = *(const f32x4*)(arow + kc);
        f32x4 xb = *(const f32x4*)(arow + kc + 4);
        f16x8 a;
        #pragma unroll
        for (int r = 0; r < 4; ++r) {
            a[r]     = (_Float16)xa[r];
            a[4 + r] = (_Float16)xb[r];
        }
        #pragma unroll
        for (int u = 0; u < 2; ++u) {
            f16x8 b = *(const f16x8*)(bbase + (size_t)(16 * u) * FF + kc);
            acc[u] = mfma16(a, b, acc[u]);
        }
    }
    #pragma unroll
    for (int u = 0; u < 2; ++u) {
        H4 o;
        #pragma unroll
        for (int r = 0; r < 4; ++r) o.h[r] = (_Float16)acc[u][r];
        *(ushort4*)(whT + (size_t)(h * 64 + th * 32 + 16 * u + iL) * NN + i0 + quad * 4) = o.u;
    }

    const float a1v0 = a1[h * 64 + th * 32 + iL];
    const float a1v1 = a1[h * 64 + th * 32 + 16 + iL];
    const float a2v0 = a2[h * 64 + th * 32 + iL];
    const float a2v1 = a2[h * 64 + th * 32 + 16 + iL];
    #pragma unroll
    for (int r = 0; r < 4; ++r) {
        float p1 = acc[0][r] * a1v0 + acc[1][r] * a1v1;
        float p2 = acc[0][r] * a2v0 + acc[1][r] * a2v1;
        #pragma unroll
        for (int off = 1; off < 16; off <<= 1) {
            p1 += __shfl_xor(p1, off);
            p2 += __shfl_xor(p2, off);
        }
        if (iL == 0) {
            sred[wave][0][quad * 4 + r] = p1;
            sred[wave][1][quad * 4 + r] = p2;
        }
    }
    __syncthreads();
    if (threadIdx.x < 64) {
        int h2  = threadIdx.x >> 4;
        int idx = threadIdx.x & 15;
        float s1 = sred[h2][0][idx] + sred[h2 + 4][0][idx];
        float s2 = sred[h2][1][idx] + sred[h2 + 4][1][idx];
        float s2l = s2 * LOG2E;
        s1L[h2 * NN + i0 + idx] = s1 * LOG2E;
        s2h[h2 * NN + i0 + idx] = (_Float16)s2l;
        float mx = s2l;
        #pragma unroll
        for (int off = 1; off < 16; off <<= 1) mx = fmaxf(mx, __shfl_xor(mx, off));
        if (idx == 0) atomicMax(m4a + h2, enc_f32(mx));
    }
}

// ---- fused masked-attention + elu + metapath sum ----
// LDS-STAGED OPERANDS (m97 pattern, wave-private): each wave's whT tile per
// it is 8KB (64 d x 64 j). It is prefetched one it ahead into a wave-private
// double-buffered LDS slot via global_load_lds (no __syncthreads in loop),
// drained by one trailing vmcnt(0) per it that hides under ~1000cyc compute.
// MFMA B-operands become ds_read_b128 (~12cyc) instead of 16-segment L2
// gathers consumed 50cyc later (the measured 70%-idle latency bottleneck,
// R1 counters). 64-row tile keeps 8 MFMA per fragment (R6's 32-row tile
// halved that and lost what occupancy gained).
// Swizzle: LDS layout byte(row,c) = row*128 + ((c^(row&7))*16). The stage
// writes linearly (base+lane*16), so the SOURCE lane mapping applies the
// inverse: lane l of call k reads whT row k*8+(l>>3), col16 (l&7)^((l>>3)&7)
// — coalescing preserved (8x128B contiguous per call). Reads use the same
// XOR: 16 iL-lanes spread over 8 bank-groups (2-way = free).
__global__ __launch_bounds__(512, 1) void k_attn(const _Float16* __restrict__ whT,
                                                 const float* __restrict__ s1L,
                                                 const _Float16* __restrict__ s2h,
                                                 const uint32_t* __restrict__ m4a,
                                                 const unsigned long long* __restrict__ bitsT,
                                                 float* __restrict__ out) {
    union __align__(16) Smem {
        _Float16 stage[8][2][4096];   // 8 waves x 2 slots x 8KB = 128KB
        struct {
            float xr[8][MM][4][16][16];  // 64KB
            float dr[8][MM][16];         // 1KB
        } epi;                           // aliased: loop done before epilogue
    };
    __shared__ Smem sm;

    const int tid  = threadIdx.x;
    const int wave = tid >> 6;
    const int lane = tid & 63;
    const int iL   = lane & 15;
    const int quad = lane >> 4;
    const int h    = blockIdx.x & 3;
    const int i0   = (blockIdx.x >> 2) * 64;      // 64 i-rows per block

    const float m4 = dec_f32(m4a[h]);
    f16x2 A2[4], B2[4];
    #pragma unroll
    for (int s = 0; s < 4; ++s) {
        float s1i = s1L[h * NN + i0 + 16 * s + iL];
        float vv  = s1i + m4;
        float cii = fmaxf(vv, ALPHA_LR * vv);     // lrelu row shift (log2 domain)
        _Float16 a = (_Float16)(s1i - cii);
        _Float16 b = (_Float16)(ALPHA_LR * s1i - cii);
        A2[s] = (f16x2){a, a};
        B2[s] = (f16x2){b, b};
    }
    const f16x2 al2 = (f16x2){(_Float16)ALPHA_LR, (_Float16)ALPHA_LR};

    f32x4 acc[4][MM][4];
    f32x4 accD[4][MM];
    #pragma unroll
    for (int s = 0; s < 4; ++s)
        #pragma unroll
        for (int m = 0; m < MM; ++m) {
            accD[s][m] = (f32x4){0.f, 0.f, 0.f, 0.f};
            #pragma unroll
            for (int t = 0; t < 4; ++t) acc[s][m][t] = (f32x4){0.f, 0.f, 0.f, 0.f};
        }

    f16x8 bones;
    #pragma unroll
    for (int e = 0; e < 8; ++e) bones[e] = (_Float16)1.0f;

    const _Float16* s2row = s2h + h * NN;
    const int qshift = quad * 8;
    const int jbase = wave * 512;

    // stage-source per-lane invariants (see swizzle derivation above)
    const _Float16* stBase = whT
        + (size_t)(h * 64 + (lane >> 3)) * NN
        + (((lane & 7) ^ ((lane >> 3) & 7)) << 3);
    // read-side per-lane byte offsets (per half), within a slot
    const int x3 = iL & 7;
    int rdOff[2];
    #pragma unroll
    for (int hf = 0; hf < 2; ++hf)
        rdOff[hf] = (iL << 7) + ((((hf << 2) + quad) ^ x3) << 4);

    _Float16* cur = &sm.stage[wave][0][0];
    _Float16* nxt = &sm.stage[wave][1][0];

    const unsigned long long* pB[MM][4];
    #pragma unroll
    for (int m = 0; m < MM; ++m)
        #pragma unroll
        for (int s = 0; s < 4; ++s)
            pB[m][s] = bitsT + (size_t)m * 64 * NN + i0 + 16 * s + iL;

    // prologue: stage it=0 and drain
    {
        const _Float16* src = stBase + jbase;
        #pragma unroll
        for (int k = 0; k < 8; ++k)
            GLOAD_LDS(src + (size_t)(k * 8) * NN, cur + k * 512);
    }
    asm volatile("s_waitcnt vmcnt(0)" ::: "memory");
    __builtin_amdgcn_sched_barrier(0);

    #pragma unroll 1
    for (int it = 0; it < 8; ++it) {
        const int jc = jbase + it * 64;
        const int jw = jc >> 6;
        // ---- VMEM phase: all L2 loads for this it, then next-it stage ----
        unsigned long long bm[MM][4];
        #pragma unroll
        for (int m = 0; m < MM; ++m)
            #pragma unroll
            for (int s = 0; s < 4; ++s)
                bm[m][s] = pB[m][s][(size_t)jw * NN];
        W8 s2vh[2];
        s2vh[0].v = *(const f16x8*)(s2row + jc + qshift);
        s2vh[1].v = *(const f16x8*)(s2row + jc + 32 + qshift);

        __builtin_amdgcn_sched_barrier(0);
        if (it < 7) {
            const _Float16* src = stBase + (jc + 64);
            #pragma unroll
            for (int k = 0; k < 8; ++k)
                GLOAD_LDS(src + (size_t)(k * 8) * NN, nxt + k * 512);
        }
        __builtin_amdgcn_sched_barrier(0);

        // ---- compute phase: LDS + VALU + MFMA only ----
        #pragma unroll
        for (int half = 0; half < 2; ++half) {
            const int shft = 32 * half + qshift;
            // B-fragments from the wave's staged slot (issued early; lgkm
            // waits are compiler-managed and hide under the P build)
            f16x8 bfr[4];
            #pragma unroll
            for (int t = 0; t < 4; ++t)
                bfr[t] = *(const f16x8*)((const char*)cur + (t << 11) + rdOff[half]);

            #pragma unroll
            for (int s = 0; s < 4; ++s) {
                uint32_t rs0 = (uint32_t)(bm[0][s] >> shft) & 0xFFu;
                uint32_t rs1 = (uint32_t)(bm[1][s] >> shft) & 0xFFu;
                uint32_t V0 = rs0 | (rs0 << 15);   // bit 2k+1 -> bit 2k+16
                uint32_t V1 = rs1 | (rs1 << 15);
                W8 a0, a1v;
                #pragma unroll
                for (int k = 0; k < 4; ++k) {
                    f16x2 z = s2vh[half].p[k] + A2[s];        // v_pk_add_f16
                    f16x2 l = al2 * s2vh[half].p[k] + B2[s];  // v_pk_fma_f16
                    f16x2 mx = pkmax(z, l);                   // v_pk_max_f16
                    f16x2 p = (f16x2){__ocml_exp2_f16(mx[0]), __ocml_exp2_f16(mx[1])};
                    a0.p[k]  = p * msk01(V0, k);              // v_pk_mul_f16
                    a1v.p[k] = p * msk01(V1, k);
                }
                #pragma unroll
                for (int t = 0; t < 4; ++t) {
                    acc[s][0][t] = mfma16(a0.v, bfr[t], acc[s][0][t]);
                    acc[s][1][t] = mfma16(a1v.v, bfr[t], acc[s][1][t]);
                }
                accD[s][0] = mfma16(a0.v, bones, accD[s][0]);
                accD[s][1] = mfma16(a1v.v, bones, accD[s][1]);
            }
        }

        // drain this it's stage (latency hidden under the compute above)
        asm volatile("s_waitcnt vmcnt(0)" ::: "memory");
        __builtin_amdgcn_sched_barrier(0);
        _Float16* tmp = cur; cur = nxt; nxt = tmp;
    }

    // ---- epilogue: per s, single 8-slot store + 4-wave finalize ----
    // leading __syncthreads also fences the stage->epi union transition
    #pragma unroll
    for (int s = 0; s < 4; ++s) {
        __syncthreads();          // previous round's reads complete
        #pragma unroll
        for (int m = 0; m < MM; ++m) {
            #pragma unroll
            for (int t = 0; t < 4; ++t)
                *(f32x4*)&sm.epi.xr[wave][m][t][iL][quad * 4] = acc[s][m][t];
            if (iL == 0) *(f32x4*)&sm.epi.dr[wave][m][quad * 4] = accD[s][m];
        }
        __syncthreads();
        if (wave < 4) {
            const int t = wave;
            f32x4 n0 = (f32x4){0.f, 0.f, 0.f, 0.f};
            f32x4 n1 = (f32x4){0.f, 0.f, 0.f, 0.f};
            f32x4 d0 = (f32x4){0.f, 0.f, 0.f, 0.f};
            f32x4 d1 = (f32x4){0.f, 0.f, 0.f, 0.f};
            #pragma unroll
            for (int sl = 0; sl < 8; ++sl) {
                n0 += *(const f32x4*)&sm.epi.xr[sl][0][t][iL][quad * 4];
                n1 += *(const f32x4*)&sm.epi.xr[sl][1][t][iL][quad * 4];
                d0 += *(const f32x4*)&sm.epi.dr[sl][0][quad * 4];
                d1 += *(const f32x4*)&sm.epi.dr[sl][1][quad * 4];
            }
            const int i0s = i0 + 16 * s;
            #pragma unroll
            for (int r = 0; r < 4; ++r) {
                float v0 = n0[r] * fast_rcp(d0[r]);
                float v1 = n1[r] * fast_rcp(d1[r]);
                float e0 = v0 > 0.f ? v0 : (fast_exp2(v0 * LOG2E) - 1.f);
                float e1 = v1 > 0.f ? v1 : (fast_exp2(v1 * LOG2E) - 1.f);
                out[(size_t)(i0s + quad * 4 + r) * (HH * DD) + h * 64 + 16 * t + iL] = e0 + e1;
            }
        }
    }
}

extern "C" void kernel_launch(void* const* d_in, const int* in_sizes, int n_in,
                              void* d_out, int out_size, void* d_ws, size_t ws_size,
                              hipStream_t stream) {
    const float* x   = (const float*)d_in[0];
    const int*   adj = (const int*)d_in[1];
    const float* W   = (const float*)d_in[2];
    const float* a1  = (const float*)d_in[3];
    const float* a2  = (const float*)d_in[4];
    // d_in[5..7] (Ws, bs, q_sem) mathematically dead: softmax over size-1 axis == 1
    float* out = (float*)d_out;

    char* ws = (char*)d_ws;
    _Float16* wt   = (_Float16*)(ws);                 // 256 KB
    _Float16* whT  = (_Float16*)(ws + 262144);        // 2 MB
    float*    s1L  = (float*)(ws + 2359296);          // 64 KB
    _Float16* s2h  = (_Float16*)(ws + 2424832);       // 32 KB
    uint32_t* m4a  = (uint32_t*)(ws + 2457600);       // 16 B
    unsigned long long* bitsT = (unsigned long long*)(ws + 2490368); // 4 MB

    hipLaunchKernelGGL(k_prep, dim3(2560), dim3(256), 0, stream,
                       adj, W, wt, bitsT, m4a);
    hipLaunchKernelGGL(k_wh, dim3(256), dim3(512), 0, stream,
                       x, wt, a1, a2, whT, s1L, s2h, m4a);
    hipLaunchKernelGGL(k_attn, dim3(256), dim3(512), 0, stream,
                       whT, s1L, s2h, m4a, bitsT, out);
}

// Round 12
// 267.409 us; speedup vs baseline: 1.0775x; 1.0131x over previous
//
#include <hip/hip_runtime.h>
#include <hip/hip_fp16.h>
#include <stdint.h>

#define NN 4096      // nodes
#define FF 512       // in features
#define DD 64        // head dim
#define HH 4         // heads
#define MM 2         // metapaths
#define LOG2E 1.44269504088896340736f
#define ALPHA_LR 0.2f

typedef float f32x4 __attribute__((ext_vector_type(4)));
typedef _Float16 f16x8 __attribute__((ext_vector_type(8)));
typedef _Float16 f16x2 __attribute__((ext_vector_type(2)));
typedef unsigned short u16x2 __attribute__((ext_vector_type(2)));

union H4 { ushort4 u; _Float16 h[4]; };
union W8 { f16x8 v; uint32_t w[4]; f16x2 p[4]; };

__device__ inline float fast_exp2(float x) { return __builtin_amdgcn_exp2f(x); }
__device__ inline float fast_rcp(float x) { return __builtin_amdgcn_rcpf(x); }
__device__ inline f32x4 mfma16(f16x8 a, f16x8 b, f32x4 c) {
    return __builtin_amdgcn_mfma_f32_16x16x32_f16(a, b, c, 0, 0, 0);
}
// order-preserving float->uint encode for atomicMax
__device__ inline uint32_t enc_f32(float f) {
    uint32_t u = __float_as_uint(f);
    return (u & 0x80000000u) ? ~u : (u | 0x80000000u);
}
__device__ inline float dec_f32(uint32_t k) {
    uint32_t u = (k & 0x80000000u) ? (k ^ 0x80000000u) : ~k;
    return __uint_as_float(u);
}
// packed f16 {0,1} mask for j-pair k from smeared bits V = rs8 | (rs8<<15)
__device__ inline f16x2 msk01(uint32_t V, int k) {
    uint32_t w = (V >> (2 * k)) & 0x00010001u;
    u16x2 m = __builtin_bit_cast(u16x2, w) * (u16x2){0x3C00, 0x3C00}; // v_pk_mul_lo_u16
    return __builtin_bit_cast(f16x2, m);
}
__device__ inline f16x2 pkmax(f16x2 a, f16x2 b) {
#if __has_builtin(__builtin_elementwise_max)
    return __builtin_elementwise_max(a, b);
#else
    return (f16x2){a[0] > b[0] ? a[0] : b[0], a[1] > b[1] ? a[1] : b[1]};
#endif
}

// global -> LDS direct (16B/lane x 64 lanes = 1KB per call); LDS dest is
// wave-uniform base + lane*16 (linear), so swizzling is done on the SOURCE
// lane->address mapping (rule: both-sides-or-neither).
#define GLOAD_LDS(G, L)                                                     \
    __builtin_amdgcn_global_load_lds(                                       \
        (const __attribute__((address_space(1))) void*)(G),                 \
        (__attribute__((address_space(3))) void*)(L), 16, 0, 0)

// ---- fused prep ----
// [0,2048): adj -> transposed bitmask. Sequential grid-stride reads (full
//           channel spread; measured-good) + ballot + lane-0 8B store.
//           Column-strip variant regressed (16KB-stride reads) — keep out.
// [2048,2560): W -> wtT f16 (+ m4a init)
__global__ __launch_bounds__(256) void k_prep(const int* __restrict__ adj,
                                              const float* __restrict__ W,
                                              _Float16* __restrict__ wt,
                                              unsigned long long* __restrict__ bitsT,
                                              uint32_t* __restrict__ m4a) {
    const int bid = blockIdx.x;
    if (bid < 2048) {
        const long long total = (long long)MM * NN * NN;      // 33554432
        const long long stride = 2048LL * 256;
        long long tid = (long long)bid * 256 + threadIdx.x;
        for (long long e = tid; e < total; e += stride) {
            unsigned long long msk = __ballot(adj[e] != 0);
            if ((threadIdx.x & 63) == 0) {
                long long q = e >> 6;
                int m  = (int)(q >> 18);
                int rem = (int)(q & 262143);
                int i  = rem >> 6;
                int jw = rem & 63;
                bitsT[((size_t)m * 64 + jw) * NN + i] = msk;
            }
        }
    } else {
        int t = (bid - 2048) * 256 + threadIdx.x;  // H*F*D = 131072
        if (t < HH) m4a[t] = 0u;                   // encoded floor
        int c = t >> 9, f = t & 511;
        int h = c >> 6, d = c & 63;
        wt[t] = (_Float16)W[(h * FF + f) * DD + d];
    }
}

// ---- Wh = x @ W[h] -> whT[h*64+d][n] f16 ; fused s1L/s2h/m4a from accumulators ----
__global__ __launch_bounds__(512) void k_wh(const float* __restrict__ x,
                                            const _Float16* __restrict__ wt,
                                            const float* __restrict__ a1,
                                            const float* __restrict__ a2,
                                            _Float16* __restrict__ whT,
                                            float* __restrict__ s1L,
                                            _Float16* __restrict__ s2h,
                                            uint32_t* __restrict__ m4a) {
    __shared__ float sred[8][2][16];
    const int wave = threadIdx.x >> 6;
    const int h    = wave & 3;
    const int th   = wave >> 2;
    const int lane = threadIdx.x & 63;
    const int iL   = lane & 15;
    const int quad = lane >> 4;
    const int i0   = blockIdx.x * 16;

    f32x4 acc[2];
    acc[0] = (f32x4){0.f, 0.f, 0.f, 0.f};
    acc[1] = (f32x4){0.f, 0.f, 0.f, 0.f};

    const float* arow = x + (size_t)(i0 + iL) * FF + quad * 8;
    const _Float16* bbase = wt + (size_t)(h * 64 + th * 32 + iL) * FF + quad * 8;

    for (int kc = 0; kc < FF; kc += 32) {
        f32x4 xa = *(const f32x4*)(arow + kc);
        f32x4 xb = *(const f32x4*)(arow + kc + 4);
        f16x8 a;
        #pragma unroll
        for (int r = 0; r < 4; ++r) {
            a[r]     = (_Float16)xa[r];
            a[4 + r] = (_Float16)xb[r];
        }
        #pragma unroll
        for (int u = 0; u < 2; ++u) {
            f16x8 b = *(const f16x8*)(bbase + (size_t)(16 * u) * FF + kc);
            acc[u] = mfma16(a, b, acc[u]);
        }
    }
    #pragma unroll
    for (int u = 0; u < 2; ++u) {
        H4 o;
        #pragma unroll
        for (int r = 0; r < 4; ++r) o.h[r] = (_Float16)acc[u][r];
        *(ushort4*)(whT + (size_t)(h * 64 + th * 32 + 16 * u + iL) * NN + i0 + quad * 4) = o.u;
    }

    const float a1v0 = a1[h * 64 + th * 32 + iL];
    const float a1v1 = a1[h * 64 + th * 32 + 16 + iL];
    const float a2v0 = a2[h * 64 + th * 32 + iL];
    const float a2v1 = a2[h * 64 + th * 32 + 16 + iL];
    #pragma unroll
    for (int r = 0; r < 4; ++r) {
        float p1 = acc[0][r] * a1v0 + acc[1][r] * a1v1;
        float p2 = acc[0][r] * a2v0 + acc[1][r] * a2v1;
        #pragma unroll
        for (int off = 1; off < 16; off <<= 1) {
            p1 += __shfl_xor(p1, off);
            p2 += __shfl_xor(p2, off);
        }
        if (iL == 0) {
            sred[wave][0][quad * 4 + r] = p1;
            sred[wave][1][quad * 4 + r] = p2;
        }
    }
    __syncthreads();
    if (threadIdx.x < 64) {
        int h2  = threadIdx.x >> 4;
        int idx = threadIdx.x & 15;
        float s1 = sred[h2][0][idx] + sred[h2 + 4][0][idx];
        float s2 = sred[h2][1][idx] + sred[h2 + 4][1][idx];
        float s2l = s2 * LOG2E;
        s1L[h2 * NN + i0 + idx] = s1 * LOG2E;
        s2h[h2 * NN + i0 + idx] = (_Float16)s2l;
        float mx = s2l;
        #pragma unroll
        for (int off = 1; off < 16; off <<= 1) mx = fmaxf(mx, __shfl_xor(mx, off));
        if (idx == 0) atomicMax(m4a + h2, enc_f32(mx));
    }
}

// ---- fused masked-attention + elu + metapath sum ----
// R7 staging kept. NEW: exp-factorization — exp2 is monotone, so
//   p(i,j) = 2^(lrelu(s1+s2)-cii) = max(u1[i]*E1[j], u2[i]*Ea[j])
// with u1 = 2^(vv-cii), u2 = 2^(a*vv-cii) (per-row, <=1, 8 exps/wave) and
// E1[j] = 2^(s2L-m4), Ea[j] = 2^(a*(s2L-m4)) (per-col, <=1, f16-safe),
// computed ONCE into a wave-private LDS table (each wave writes exactly its
// own 512-j slice -> no sync). Inner (s,half,k) body: 2 pk_mul + pk_max +
// mask-muls — the 64 transcendental exps + 32 pk_add/fma PER IT are gone.
// R1 counters showed VALUBusy 2.2x MfmaUtil: this VALU/trans stream is what
// competes with MFMA issue (MFMA-pipe floor for this kernel is ~17us).
__global__ __launch_bounds__(512, 1) void k_attn(const _Float16* __restrict__ whT,
                                                 const float* __restrict__ s1L,
                                                 const _Float16* __restrict__ s2h,
                                                 const uint32_t* __restrict__ m4a,
                                                 const unsigned long long* __restrict__ bitsT,
                                                 float* __restrict__ out) {
    struct __align__(16) Smem {
        union {
            _Float16 stage[8][2][4096];      // 8 waves x 2 slots x 8KB = 128KB
            struct {
                float xr[8][MM][4][16][16];  // 64KB
                float dr[8][MM][16];         // 1KB
            } epi;                           // aliased: loop done before epilogue
        };
        _Float16 e1[8][512];                 // 8KB  (persists through loop)
        _Float16 ea[8][512];                 // 8KB
    };
    __shared__ Smem sm;

    const int tid  = threadIdx.x;
    const int wave = tid >> 6;
    const int lane = tid & 63;
    const int iL   = lane & 15;
    const int quad = lane >> 4;
    const int h    = blockIdx.x & 3;
    const int i0   = (blockIdx.x >> 2) * 64;      // 64 i-rows per block

    const int qshift = quad * 8;
    const int jbase = wave * 512;

    const float m4 = dec_f32(m4a[h]);

    // ---- wave-private E tables: E1/Ea for this wave's 512-j slice ----
    {
        f16x8 sv = *(const f16x8*)(s2h + h * NN + jbase + lane * 8);
        f16x8 e1v8, eav8;
        #pragma unroll
        for (int e = 0; e < 8; ++e) {
            float sf = (float)sv[e] - m4;          // <= 0
            e1v8[e] = (_Float16)fast_exp2(sf);
            eav8[e] = (_Float16)fast_exp2(ALPHA_LR * sf);
        }
        *(f16x8*)&sm.e1[wave][lane * 8] = e1v8;
        *(f16x8*)&sm.ea[wave][lane * 8] = eav8;
    }

    // ---- per-row factors u1,u2 (<=1): p = max(u1*E1, u2*Ea) ----
    f16x2 U1[4], U2[4];
    #pragma unroll
    for (int s = 0; s < 4; ++s) {
        float s1i = s1L[h * NN + i0 + 16 * s + iL];
        float vv  = s1i + m4;
        float cii = fmaxf(vv, ALPHA_LR * vv);      // lrelu row shift (log2 domain)
        _Float16 a = (_Float16)fast_exp2(vv - cii);
        _Float16 b = (_Float16)fast_exp2(ALPHA_LR * vv - cii);
        U1[s] = (f16x2){a, a};
        U2[s] = (f16x2){b, b};
    }

    f32x4 acc[4][MM][4];
    f32x4 accD[4][MM];
    #pragma unroll
    for (int s = 0; s < 4; ++s)
        #pragma unroll
        for (int m = 0; m < MM; ++m) {
            accD[s][m] = (f32x4){0.f, 0.f, 0.f, 0.f};
            #pragma unroll
            for (int t = 0; t < 4; ++t) acc[s][m][t] = (f32x4){0.f, 0.f, 0.f, 0.f};
        }

    f16x8 bones;
    #pragma unroll
    for (int e = 0; e < 8; ++e) bones[e] = (_Float16)1.0f;

    // stage-source per-lane invariants (swizzle: lane l of call k reads whT
    // row k*8+(l>>3), col16 (l&7)^((l>>3)&7); reads use the same XOR)
    const _Float16* stBase = whT
        + (size_t)(h * 64 + (lane >> 3)) * NN
        + (((lane & 7) ^ ((lane >> 3) & 7)) << 3);
    const int x3 = iL & 7;
    int rdOff[2];
    #pragma unroll
    for (int hf = 0; hf < 2; ++hf)
        rdOff[hf] = (iL << 7) + ((((hf << 2) + quad) ^ x3) << 4);

    _Float16* cur = &sm.stage[wave][0][0];
    _Float16* nxt = &sm.stage[wave][1][0];

    const unsigned long long* pB[MM][4];
    #pragma unroll
    for (int m = 0; m < MM; ++m)
        #pragma unroll
        for (int s = 0; s < 4; ++s)
            pB[m][s] = bitsT + (size_t)m * 64 * NN + i0 + 16 * s + iL;

    // prologue: stage it=0 and drain
    {
        const _Float16* src = stBase + jbase;
        #pragma unroll
        for (int k = 0; k < 8; ++k)
            GLOAD_LDS(src + (size_t)(k * 8) * NN, cur + k * 512);
    }
    asm volatile("s_waitcnt vmcnt(0)" ::: "memory");
    __builtin_amdgcn_sched_barrier(0);

    #pragma unroll 1
    for (int it = 0; it < 8; ++it) {
        const int jc = jbase + it * 64;
        const int jw = jc >> 6;
        // ---- VMEM phase: bm loads, then next-it stage ----
        unsigned long long bm[MM][4];
        #pragma unroll
        for (int m = 0; m < MM; ++m)
            #pragma unroll
            for (int s = 0; s < 4; ++s)
                bm[m][s] = pB[m][s][(size_t)jw * NN];

        __builtin_amdgcn_sched_barrier(0);
        if (it < 7) {
            const _Float16* src = stBase + (jc + 64);
            #pragma unroll
            for (int k = 0; k < 8; ++k)
                GLOAD_LDS(src + (size_t)(k * 8) * NN, nxt + k * 512);
        }
        __builtin_amdgcn_sched_barrier(0);

        // ---- compute phase: LDS + VALU + MFMA only ----
        #pragma unroll
        for (int half = 0; half < 2; ++half) {
            const int shft = 32 * half + qshift;
            const int eo = it * 64 + 32 * half + qshift;  // table index (broadcast)
            W8 e1h_, eah_;
            e1h_.v = *(const f16x8*)&sm.e1[wave][eo];
            eah_.v = *(const f16x8*)&sm.ea[wave][eo];
            f16x8 bfr[4];
            #pragma unroll
            for (int t = 0; t < 4; ++t)
                bfr[t] = *(const f16x8*)((const char*)cur + (t << 11) + rdOff[half]);

            #pragma unroll
            for (int s = 0; s < 4; ++s) {
                uint32_t rs0 = (uint32_t)(bm[0][s] >> shft) & 0xFFu;
                uint32_t rs1 = (uint32_t)(bm[1][s] >> shft) & 0xFFu;
                uint32_t V0 = rs0 | (rs0 << 15);   // bit 2k+1 -> bit 2k+16
                uint32_t V1 = rs1 | (rs1 << 15);
                W8 a0, a1v;
                #pragma unroll
                for (int k = 0; k < 4; ++k) {
                    f16x2 w1 = U1[s] * e1h_.p[k];             // v_pk_mul_f16
                    f16x2 w2 = U2[s] * eah_.p[k];             // v_pk_mul_f16
                    f16x2 p  = pkmax(w1, w2);                 // v_pk_max_f16
                    a0.p[k]  = p * msk01(V0, k);              // v_pk_mul_f16
                    a1v.p[k] = p * msk01(V1, k);
                }
                #pragma unroll
                for (int t = 0; t < 4; ++t) {
                    acc[s][0][t] = mfma16(a0.v, bfr[t], acc[s][0][t]);
                    acc[s][1][t] = mfma16(a1v.v, bfr[t], acc[s][1][t]);
                }
                accD[s][0] = mfma16(a0.v, bones, accD[s][0]);
                accD[s][1] = mfma16(a1v.v, bones, accD[s][1]);
            }
        }

        // drain this it's stage (latency hidden under the compute above)
        asm volatile("s_waitcnt vmcnt(0)" ::: "memory");
        __builtin_amdgcn_sched_barrier(0);
        _Float16* tmp = cur; cur = nxt; nxt = tmp;
    }

    // ---- epilogue: per s, single 8-slot store + 4-wave finalize ----
    // leading __syncthreads also fences the stage->epi union transition
    #pragma unroll
    for (int s = 0; s < 4; ++s) {
        __syncthreads();          // previous round's reads complete
        #pragma unroll
        for (int m = 0; m < MM; ++m) {
            #pragma unroll
            for (int t = 0; t < 4; ++t)
                *(f32x4*)&sm.epi.xr[wave][m][t][iL][quad * 4] = acc[s][m][t];
            if (iL == 0) *(f32x4*)&sm.epi.dr[wave][m][quad * 4] = accD[s][m];
        }
        __syncthreads();
        if (wave < 4) {
            const int t = wave;
            f32x4 n0 = (f32x4){0.f, 0.f, 0.f, 0.f};
            f32x4 n1 = (f32x4){0.f, 0.f, 0.f, 0.f};
            f32x4 d0 = (f32x4){0.f, 0.f, 0.f, 0.f};
            f32x4 d1 = (f32x4){0.f, 0.f, 0.f, 0.f};
            #pragma unroll
            for (int sl = 0; sl < 8; ++sl) {
                n0 += *(const f32x4*)&sm.epi.xr[sl][0][t][iL][quad * 4];
                n1 += *(const f32x4*)&sm.epi.xr[sl][1][t][iL][quad * 4];
                d0 += *(const f32x4*)&sm.epi.dr[sl][0][quad * 4];
                d1 += *(const f32x4*)&sm.epi.dr[sl][1][quad * 4];
            }
            const int i0s = i0 + 16 * s;
            #pragma unroll
            for (int r = 0; r < 4; ++r) {
                float v0 = n0[r] * fast_rcp(d0[r]);
                float v1 = n1[r] * fast_rcp(d1[r]);
                float e0 = v0 > 0.f ? v0 : (fast_exp2(v0 * LOG2E) - 1.f);
                float e1 = v1 > 0.f ? v1 : (fast_exp2(v1 * LOG2E) - 1.f);
                out[(size_t)(i0s + quad * 4 + r) * (HH * DD) + h * 64 + 16 * t + iL] = e0 + e1;
            }
        }
    }
}

extern "C" void kernel_launch(void* const* d_in, const int* in_sizes, int n_in,
                              void* d_out, int out_size, void* d_ws, size_t ws_size,
                              hipStream_t stream) {
    const float* x   = (const float*)d_in[0];
    const int*   adj = (const int*)d_in[1];
    const float* W   = (const float*)d_in[2];
    const float* a1  = (const float*)d_in[3];
    const float* a2  = (const float*)d_in[4];
    // d_in[5..7] (Ws, bs, q_sem) mathematically dead: softmax over size-1 axis == 1
    float* out = (float*)d_out;

    char* ws = (char*)d_ws;
    _Float16* wt   = (_Float16*)(ws);                 // 256 KB
    _Float16* whT  = (_Float16*)(ws + 262144);        // 2 MB
    float*    s1L  = (float*)(ws + 2359296);          // 64 KB
    _Float16* s2h  = (_Float16*)(ws + 2424832);       // 32 KB
    uint32_t* m4a  = (uint32_t*)(ws + 2457600);       // 16 B
    unsigned long long* bitsT = (unsigned long long*)(ws + 2490368); // 4 MB

    hipLaunchKernelGGL(k_prep, dim3(2560), dim3(256), 0, stream,
                       adj, W, wt, bitsT, m4a);
    hipLaunchKernelGGL(k_wh, dim3(256), dim3(512), 0, stream,
                       x, wt, a1, a2, whT, s1L, s2h, m4a);
    hipLaunchKernelGGL(k_attn, dim3(256), dim3(512), 0, stream,
                       whT, s1L, s2h, m4a, bitsT, out);
}